// Round 2
// baseline (399.401 us; speedup 1.0000x reference)
//
#include <hip/hip_runtime.h>
#include <stdint.h>

// ---------------------------------------------------------------------------
// GCN block: 3 x [ h = leaky_relu(in @ W);  out = (adj + I) @ h ]
// B=64, N=4096, D=16.  Heavy op per layer: GEMM M=4096 x Ncols=1024 x K=4096
// in bf16 MFMA, fp32 accum.  adjI = adj + I folded once.
// Round 2: 128x128x64 tile, 8 waves, LDS double-buffer (1 barrier/iter),
// XOR-swizzled LDS (conflict-free ds_read_b128), grid 256 XCD-swizzled.
// Workspace: adjI bf16 [4096][4096] | hT bf16 [1024][4096] | out fp32 [4096][1024]
// ---------------------------------------------------------------------------

typedef __bf16 bf16x8 __attribute__((ext_vector_type(8)));
typedef float  f32x4  __attribute__((ext_vector_type(4)));
typedef unsigned short ushort8 __attribute__((ext_vector_type(8)));

typedef __attribute__((address_space(1))) void* as1_void_p;
typedef __attribute__((address_space(3))) void* as3_void_p;

// async 16B/lane global->LDS (lds dest wave-uniform base; HW adds lane*16)
#define GLOAD_LDS16(G, L)                                                      \
  __builtin_amdgcn_global_load_lds((as1_void_p)(G), (as3_void_p)(L), 16, 0, 0)

__device__ __forceinline__ unsigned short f2bf(float f) {
  unsigned u = __float_as_uint(f);
  u += 0x7fffu + ((u >> 16) & 1u);  // RNE
  return (unsigned short)(u >> 16);
}

// ---------------------------------------------------------------------------
// adjI = bf16(adj + I), 4096x4096.  1 thread = 16 contiguous elements.
// ---------------------------------------------------------------------------
__global__ void make_adjI(const float* __restrict__ adj,
                          unsigned short* __restrict__ adjb) {
  size_t t = (size_t)blockIdx.x * 256 + threadIdx.x;
  size_t base = t * 16;
  int n  = (int)(base >> 12);
  int m0 = (int)(base & 4095);
  const float4* src = (const float4*)(adj + base);
  float4 q0 = src[0], q1 = src[1], q2 = src[2], q3 = src[3];
  float vals[16] = {q0.x,q0.y,q0.z,q0.w, q1.x,q1.y,q1.z,q1.w,
                    q2.x,q2.y,q2.z,q2.w, q3.x,q3.y,q3.z,q3.w};
  ushort8 o0, o1;
#pragma unroll
  for (int j = 0; j < 8; j++) {
    float f = vals[j];     if (m0 + j == n)     f += 1.0f;
    o0[j] = f2bf(f);
  }
#pragma unroll
  for (int j = 0; j < 8; j++) {
    float f = vals[8 + j]; if (m0 + 8 + j == n) f += 1.0f;
    o1[j] = f2bf(f);
  }
  ushort8* dst = (ushort8*)(adjb + base);
  dst[0] = o0; dst[1] = o1;
}

// ---------------------------------------------------------------------------
// h = leaky_relu(in @ W), written TRANSPOSED as bf16: hb[c][m], c=b*16+e, m=n.
// ---------------------------------------------------------------------------
__global__ void linear_pack(const float* __restrict__ in,
                            const float* __restrict__ W,
                            unsigned short* __restrict__ hb, int in_bnd) {
  int tid  = threadIdx.x;
  int lane = tid & 63;
  int bq   = tid >> 6;
  int n = blockIdx.x * 64 + lane;
  int b = blockIdx.y * 4 + bq;
  size_t off = in_bnd ? (((size_t)b * 4096 + n) * 16)
                      : ((size_t)n * 1024 + b * 16);
  const float4* src = (const float4*)(in + off);
  float4 q0 = src[0], q1 = src[1], q2 = src[2], q3 = src[3];
  float xr[16] = {q0.x,q0.y,q0.z,q0.w, q1.x,q1.y,q1.z,q1.w,
                  q2.x,q2.y,q2.z,q2.w, q3.x,q3.y,q3.z,q3.w};
#pragma unroll
  for (int e = 0; e < 16; e++) {
    float acc = 0.f;
#pragma unroll
    for (int d = 0; d < 16; d++) acc += xr[d] * W[d * 16 + e];
    acc = acc > 0.f ? acc : 0.2f * acc;
    hb[(size_t)(b * 16 + e) * 4096 + n] = f2bf(acc);
  }
}

// ---------------------------------------------------------------------------
// out[n][c] = sum_m adjI[n][m] * hT[c][m].
// Tile BM=128, BN=128, BK=64.  8 waves (2m x 4n), wave tile 64x32.
// LDS rows are 64 bf16 = 128B = 8 x 16B chunks; phys chunk = logical ^ (row&7)
// (swizzle applied on the GLOBAL address so global_load_lds stays legal).
// Double-buffered: prefetch k+1 before compute k; one __syncthreads per iter
// (its vmcnt(0) drain lands after the MFMA body -> overlap).
// ---------------------------------------------------------------------------
__global__ __launch_bounds__(512, 2)
void gemm_adj(const unsigned short* __restrict__ A,
              const unsigned short* __restrict__ Bm,
              float* __restrict__ out, int final_mode) {
  const int K = 4096;
  __shared__ __bf16 a_s[2][128 * 64];   // 2 x 16 KB
  __shared__ __bf16 b_s[2][128 * 64];   // 2 x 16 KB

  int tid  = threadIdx.x;
  int wave = tid >> 6, lane = tid & 63;

  int lin = blockIdx.x;              // 0..255
  int xcd = lin & 7, ii = lin >> 3;  // per XCD: 4 m-tiles x 8 c-tiles
  int mt = xcd * 4 + (ii & 3);       // 0..31
  int ct = ii >> 2;                  // 0..7
  int n0 = mt * 128, c0 = ct * 128;

  // --- staging: 2 insts per operand per wave, 8 rows x 8 chunks each ---
  int l8 = lane >> 3;                // row within 8-row chunk
  int lc = lane & 7;                 // phys 16B chunk within row
  int sw = lc ^ l8;                  // logical chunk (XOR swizzle)
  int r0 = (wave * 2 + 0) * 8 + l8;  // tile rows covered by inst 0 / inst 1
  int r1 = (wave * 2 + 1) * 8 + l8;
  const unsigned short* gA0 = A  + (size_t)(n0 + r0) * K + sw * 8;
  const unsigned short* gA1 = A  + (size_t)(n0 + r1) * K + sw * 8;
  const unsigned short* gB0 = Bm + (size_t)(c0 + r0) * K + sw * 8;
  const unsigned short* gB1 = Bm + (size_t)(c0 + r1) * K + sw * 8;
  int lds0 = (wave * 2 + 0) * 512;   // elems: 8 rows * 64
  int lds1 = (wave * 2 + 1) * 512;

  // --- MFMA fragment addressing ---
  int i16 = lane & 15, q = lane >> 4;
  int wm = wave >> 2, wn = wave & 3;           // wave grid 2 x 4
  int aRow = wm * 64 + i16;                    // + t*16
  int bRow = wn * 32 + i16;                    // + u*16
  int sw7 = i16 & 7;

  f32x4 acc[4][2] = {};

  // prefetch iter 0 into buf 0
  GLOAD_LDS16(gA0, &a_s[0][lds0]);
  GLOAD_LDS16(gA1, &a_s[0][lds1]);
  GLOAD_LDS16(gB0, &b_s[0][lds0]);
  GLOAD_LDS16(gB1, &b_s[0][lds1]);

  for (int it = 0; it < 64; ++it) {
    __syncthreads();                 // drains prefetch(it); prev reads done
    if (it + 1 < 64) {
      int k0 = (it + 1) * 64;
      int nb = (it + 1) & 1;
      GLOAD_LDS16(gA0 + k0, &a_s[nb][lds0]);
      GLOAD_LDS16(gA1 + k0, &a_s[nb][lds1]);
      GLOAD_LDS16(gB0 + k0, &b_s[nb][lds0]);
      GLOAD_LDS16(gB1 + k0, &b_s[nb][lds1]);
    }
    const __bf16* ab = a_s[it & 1];
    const __bf16* bb = b_s[it & 1];
#pragma unroll
    for (int s = 0; s < 2; ++s) {
      int pc = (s * 4 + q) ^ sw7;    // phys chunk for this frag read
      bf16x8 b0 = *(const bf16x8*)(bb + (bRow +  0) * 64 + pc * 8);
      bf16x8 b1 = *(const bf16x8*)(bb + (bRow + 16) * 64 + pc * 8);
#pragma unroll
      for (int t = 0; t < 4; ++t) {
        bf16x8 a = *(const bf16x8*)(ab + (aRow + t * 16) * 64 + pc * 8);
        acc[t][0] = __builtin_amdgcn_mfma_f32_16x16x32_bf16(a, b0, acc[t][0], 0, 0, 0);
        acc[t][1] = __builtin_amdgcn_mfma_f32_16x16x32_bf16(a, b1, acc[t][1], 0, 0, 0);
      }
    }
  }

  // epilogue: D[row=q*4+i][col=i16] per 16x16 tile
#pragma unroll
  for (int t = 0; t < 4; t++)
#pragma unroll
    for (int u = 0; u < 2; u++)
#pragma unroll
      for (int i = 0; i < 4; i++) {
        int n_g = n0 + wm * 64 + t * 16 + q * 4 + i;
        int c_g = c0 + wn * 32 + u * 16 + i16;
        float v = acc[t][u][i];
        if (final_mode)
          out[((size_t)(c_g >> 4) * 4096 + n_g) * 16 + (c_g & 15)] = v;
        else
          out[(size_t)n_g * 1024 + c_g] = v;
      }
}

// ---------------------------------------------------------------------------
extern "C" void kernel_launch(void* const* d_in, const int* in_sizes, int n_in,
                              void* d_out, int out_size, void* d_ws, size_t ws_size,
                              hipStream_t stream) {
  const float* x   = (const float*)d_in[0];
  const float* adj = (const float*)d_in[1];
  // d_in[2] = Identity (folded analytically)
  const float* W0  = (const float*)d_in[3];
  const float* W1  = (const float*)d_in[4];
  const float* W2  = (const float*)d_in[5];
  float* out = (float*)d_out;

  char* ws = (char*)d_ws;
  unsigned short* adjb = (unsigned short*)ws;                 // 32 MiB
  unsigned short* hb   = (unsigned short*)(ws + 33554432);    //  8 MiB
  float*          ows  = (float*)(ws + 33554432 + 8388608);   // 16 MiB

  make_adjI<<<4096, 256, 0, stream>>>(adj, adjb);

  linear_pack<<<dim3(64, 16), 256, 0, stream>>>(x, W0, hb, 1);
  gemm_adj<<<256, 512, 0, stream>>>(adjb, hb, ows, 0);

  linear_pack<<<dim3(64, 16), 256, 0, stream>>>(ows, W1, hb, 0);
  gemm_adj<<<256, 512, 0, stream>>>(adjb, hb, ows, 0);

  linear_pack<<<dim3(64, 16), 256, 0, stream>>>(ows, W2, hb, 0);
  gemm_adj<<<256, 512, 0, stream>>>(adjb, hb, out, 1);
}